// Round 3
// baseline (1117.921 us; speedup 1.0000x reference)
//
#include <hip/hip_runtime.h>
#include <hip/hip_bf16.h>

#define DIN 128
#define DH 32
#define DOUT 2
#define NPB 128            // nodes per bucket
#define NPB_SHIFT 7
#define NBUK_MAX 1024      // supports n <= 131072 (17-bit src packing)
#define FILL_EDGES 2048    // edges per hist/fill block (small -> high occupancy)
#define ECHUNK 2048        // agg1 staged edge chunk

// fixed-point scales for LDS integer accumulation (atomicAdd(int*) -> ds_add_u32;
// float atomicAdd on LDS is a CAS loop = round-1's 12x regression)
#define FXS1 262144.0f            // 2^18
#define FXI1 (1.0f / 262144.0f)
#define FXS2 131072.0f            // 2^17
#define FXI2 (1.0f / 131072.0f)

// ---------------------------------------------------------------------------
// workspace (~20.9 MB):
//   dinv float[n]
//   gcnt int[NBUK_MAX]; degarr int[n]     <- contiguous, one memset
//   gbase/gcur int[NBUK_MAX]
//   binned uint[E]: (dst&127)<<17 | src grouped by bucket
//   mqc bf16[(n+1)*32]: dinv-scaled layer-1 messages + ZERO sentinel row n
//   m2q float2[n]
// ---------------------------------------------------------------------------

__device__ inline unsigned short f2bf(float f) {
    unsigned int u = __float_as_uint(f);
    u = (u + 0x7FFFu + ((u >> 16) & 1u)) >> 16;
    return (unsigned short)u;
}
__device__ inline float bfLO(unsigned int w) { return __uint_as_float(w << 16); }
__device__ inline float bfHI(unsigned int w) { return __uint_as_float(w & 0xFFFF0000u); }

// bucket-level histogram + per-node degree (fire-and-forget global atomics)
__global__ void __launch_bounds__(256, 8)
bukhist_kernel(const int* __restrict__ dst, int* __restrict__ gcnt,
               int* __restrict__ degarr, int e, int nbuk) {
    __shared__ int lcnt[NBUK_MAX];
    int t = threadIdx.x;
    for (int i = t; i < nbuk; i += 256) lcnt[i] = 0;
    __syncthreads();
    int e0 = blockIdx.x * FILL_EDGES;
    int m = min(FILL_EDGES, e - e0);
    for (int i = t; i < m; i += 256) {
        int d = dst[e0 + i];
        atomicAdd(&lcnt[d >> NPB_SHIFT], 1);
        atomicAdd(&degarr[d], 1);          // no-return global atomic, pipelined
    }
    __syncthreads();
    for (int i = t; i < nbuk; i += 256)
        if (lcnt[i]) atomicAdd(&gcnt[i], lcnt[i]);
}

// single-block exclusive scan of gcnt[nbuk] -> gbase, gcur; also zeroes the
// mqc sentinel row n (agg1's padded slots gather it -> adds exact 0)
__global__ void scan_kernel(const int* __restrict__ gcnt, int* __restrict__ gbase,
                            int* __restrict__ gcur, int nbuk,
                            unsigned short* __restrict__ mqc, int n) {
    __shared__ int sd[256];
    int t = threadIdx.x;
    if (t < 16) ((unsigned int*)(mqc + (size_t)n * DH))[t] = 0u;
    int v[4], s = 0;
#pragma unroll
    for (int k = 0; k < 4; ++k) {
        int i = 4 * t + k;
        v[k] = (i < nbuk) ? gcnt[i] : 0;
        s += v[k];
    }
    sd[t] = s;
    __syncthreads();
    for (int off = 1; off < 256; off <<= 1) {
        int x = (t >= off) ? sd[t - off] : 0;
        __syncthreads();
        sd[t] += x;
        __syncthreads();
    }
    int run = sd[t] - s;
#pragma unroll
    for (int k = 0; k < 4; ++k) {
        int i = 4 * t + k;
        if (i < nbuk) { gbase[i] = run; gcur[i] = run; }
        run += v[k];
    }
}

// hist -> reserve (global atomic on gcur) -> direct scattered global write.
// No LDS sort: 8 KB LDS -> 8 blocks/CU; scattered 4B writes absorbed by L2.
__global__ void __launch_bounds__(256, 8)
binfill_kernel(const int* __restrict__ src, const int* __restrict__ dst,
               int* __restrict__ gcur, unsigned int* __restrict__ binned,
               int e, int nbuk) {
    __shared__ int cnt[NBUK_MAX];
    __shared__ int pos[NBUK_MAX];
    int t = threadIdx.x;
    int e0 = blockIdx.x * FILL_EDGES;
    int m = min(FILL_EDGES, e - e0);

    for (int i = t; i < nbuk; i += 256) cnt[i] = 0;
    __syncthreads();
    for (int i = t; i < m; i += 256) atomicAdd(&cnt[dst[e0 + i] >> NPB_SHIFT], 1);
    __syncthreads();
    for (int b = t; b < nbuk; b += 256) {
        int c = cnt[b];
        pos[b] = c ? atomicAdd(&gcur[b], c) : 0;
    }
    __syncthreads();
    for (int i = t; i < m; i += 256) {
        int d = dst[e0 + i];
        int sv = src[e0 + i];
        int b = d >> NPB_SHIFT;
        int slot = atomicAdd(&pos[b], 1);
        binned[slot] = ((unsigned int)(d & (NPB - 1)) << 17) | (unsigned int)sv;
    }
}

// mqc[r][c] = (x[r]·W1[:,c]) * dinv[r], bf16; dinv computed inline from degarr
#define XLD 132
__global__ void gemm1_kernel(const float* __restrict__ x, const float* __restrict__ W1,
                             const int* __restrict__ degarr, float* __restrict__ dinv,
                             unsigned short* __restrict__ mqc, int n) {
    __shared__ float  Xl[32 * XLD];
    __shared__ float4 Wl4[DIN * 8];

    int t = threadIdx.x;
    for (int i = t; i < DIN * 8; i += 256) Wl4[i] = ((const float4*)W1)[i];

    int rb = blockIdx.x * 32;
    for (int i = t; i < 32 * 32; i += 256) {
        int rr = i >> 5, c4 = i & 31;
        int gr = rb + rr;
        float4 v = make_float4(0.f, 0.f, 0.f, 0.f);
        if (gr < n) v = ((const float4*)x)[(size_t)gr * 32 + c4];
        ((float4*)Xl)[rr * 33 + c4] = v;
    }
    __syncthreads();

    const int lane = t & 7;
    const int row  = t >> 3;
    const float* xrow = &Xl[row * XLD];
    float4 acc = make_float4(0.f, 0.f, 0.f, 0.f);
#pragma unroll
    for (int k = 0; k < DIN; ++k) {
        float xv = xrow[k];
        float4 w = Wl4[k * 8 + lane];
        acc.x += xv * w.x; acc.y += xv * w.y;
        acc.z += xv * w.z; acc.w += xv * w.w;
    }
    int r = rb + row;
    if (r < n) {
        float di = rsqrtf((float)(degarr[r] + 1));
        if (lane == 0) dinv[r] = di;
        ushort4 sv;
        sv.x = f2bf(acc.x * di); sv.y = f2bf(acc.y * di);
        sv.z = f2bf(acc.z * di); sv.w = f2bf(acc.w * di);
        *(ushort4*)&mqc[(size_t)r * DH + 4 * lane] = sv;
    }
}

// one block per bucket, 512 threads (24 waves/CU).  Edges staged into LDS in
// double-buffered 2048-edge chunks (kills the per-iteration L2-latency on the
// edge stream); 32 gather-groups of 16 lanes; x8 unroll = 8 gathers in
// flight/group; fixed-point ds_add accumulation; sentinel edge = n (mqc row n
// is zeroed) -> zero predication in the hot loop.
__global__ void __launch_bounds__(512, 6)
agg1_kernel(const int* __restrict__ gbase, const int* __restrict__ gcnt,
            const unsigned int* __restrict__ binned,
            const unsigned short* __restrict__ mqc,
            const float* __restrict__ dinv,
            const float* __restrict__ b1, const float* __restrict__ W2,
            float2* __restrict__ m2q, int n) {
    __shared__ int acc[NPB * 33];                 // 16.9 KB
    __shared__ unsigned int ebuf[2][ECHUNK];      // 16 KB

    const int t = threadIdx.x;
    const int b = blockIdx.x;
    const int beg = gbase[b];
    const int cntb = gcnt[b];
    const int r0 = b << NPB_SHIFT;

    for (int i = t; i < NPB * 33; i += 512) acc[i] = 0;

    const unsigned int* __restrict__ bp = binned + beg;
    const unsigned int* __restrict__ mq32 = (const unsigned int*)mqc;
    const unsigned int sent = (unsigned int)n;
    const int nchunks = (cntb + ECHUNK - 1) / ECHUNK;

    unsigned int st[4];
    if (nchunks > 0) {
#pragma unroll
        for (int k = 0; k < 4; ++k) {
            int idx = t + k * 512;
            st[k] = (idx < cntb) ? __builtin_nontemporal_load(&bp[idx]) : sent;
        }
#pragma unroll
        for (int k = 0; k < 4; ++k) ebuf[0][t + k * 512] = st[k];
    }
    __syncthreads();

    const int g = t >> 4, l = t & 15;

    for (int c = 0; c < nchunks; ++c) {
        if (c + 1 < nchunks) {
            const int base = (c + 1) * ECHUNK;
#pragma unroll
            for (int k = 0; k < 4; ++k) {
                int idx = base + t + k * 512;
                st[k] = (idx < cntb) ? __builtin_nontemporal_load(&bp[idx]) : sent;
            }
        }
        const unsigned int* eb = ebuf[c & 1];
        for (int j = 0; j < 64; j += 8) {
            const unsigned int* ej = &eb[g + 32 * j];
            unsigned int e0 = ej[0],   e1 = ej[32],  e2 = ej[64],  e3 = ej[96];
            unsigned int e4 = ej[128], e5 = ej[160], e6 = ej[192], e7 = ej[224];
            unsigned int w0 = mq32[(e0 & 0x1FFFFu) * 16u + l];
            unsigned int w1 = mq32[(e1 & 0x1FFFFu) * 16u + l];
            unsigned int w2 = mq32[(e2 & 0x1FFFFu) * 16u + l];
            unsigned int w3 = mq32[(e3 & 0x1FFFFu) * 16u + l];
            unsigned int w4 = mq32[(e4 & 0x1FFFFu) * 16u + l];
            unsigned int w5 = mq32[(e5 & 0x1FFFFu) * 16u + l];
            unsigned int w6 = mq32[(e6 & 0x1FFFFu) * 16u + l];
            unsigned int w7 = mq32[(e7 & 0x1FFFFu) * 16u + l];
            int d0 = (int)(e0 >> 17) * 33 + 2 * l;
            int d1 = (int)(e1 >> 17) * 33 + 2 * l;
            int d2 = (int)(e2 >> 17) * 33 + 2 * l;
            int d3 = (int)(e3 >> 17) * 33 + 2 * l;
            int d4 = (int)(e4 >> 17) * 33 + 2 * l;
            int d5 = (int)(e5 >> 17) * 33 + 2 * l;
            int d6 = (int)(e6 >> 17) * 33 + 2 * l;
            int d7 = (int)(e7 >> 17) * 33 + 2 * l;
            atomicAdd(&acc[d0], __float2int_rn(bfLO(w0) * FXS1));
            atomicAdd(&acc[d0 + 1], __float2int_rn(bfHI(w0) * FXS1));
            atomicAdd(&acc[d1], __float2int_rn(bfLO(w1) * FXS1));
            atomicAdd(&acc[d1 + 1], __float2int_rn(bfHI(w1) * FXS1));
            atomicAdd(&acc[d2], __float2int_rn(bfLO(w2) * FXS1));
            atomicAdd(&acc[d2 + 1], __float2int_rn(bfHI(w2) * FXS1));
            atomicAdd(&acc[d3], __float2int_rn(bfLO(w3) * FXS1));
            atomicAdd(&acc[d3 + 1], __float2int_rn(bfHI(w3) * FXS1));
            atomicAdd(&acc[d4], __float2int_rn(bfLO(w4) * FXS1));
            atomicAdd(&acc[d4 + 1], __float2int_rn(bfHI(w4) * FXS1));
            atomicAdd(&acc[d5], __float2int_rn(bfLO(w5) * FXS1));
            atomicAdd(&acc[d5 + 1], __float2int_rn(bfHI(w5) * FXS1));
            atomicAdd(&acc[d6], __float2int_rn(bfLO(w6) * FXS1));
            atomicAdd(&acc[d6 + 1], __float2int_rn(bfHI(w6) * FXS1));
            atomicAdd(&acc[d7], __float2int_rn(bfLO(w7) * FXS1));
            atomicAdd(&acc[d7 + 1], __float2int_rn(bfHI(w7) * FXS1));
        }
        __syncthreads();
        if (c + 1 < nchunks) {
#pragma unroll
            for (int k = 0; k < 4; ++k) ebuf[(c + 1) & 1][t + k * 512] = st[k];
        }
        __syncthreads();
    }

    // epilogue: 4 threads per node (8 dims each): self + ReLU + W2
    const int j = t >> 2, q = t & 3;
    const int r = r0 + j;
    if (r < n) {
        const float di = dinv[r];
        const unsigned int* srow = mq32 + (size_t)r * 16 + q * 4;
        const int* ar = &acc[j * 33 + q * 8];
        float p0 = 0.f, p1 = 0.f;
#pragma unroll
        for (int k = 0; k < 4; ++k) {
            unsigned int sw = srow[k];
            int c = q * 8 + 2 * k;
            float a0 = (float)ar[2 * k]     * FXI1;
            float a1 = (float)ar[2 * k + 1] * FXI1;
            float h0 = fmaxf(di * (a0 + bfLO(sw)) + b1[c],     0.0f);
            float h1 = fmaxf(di * (a1 + bfHI(sw)) + b1[c + 1], 0.0f);
            p0 += h0 * W2[2 * c]     + h1 * W2[2 * c + 2];
            p1 += h0 * W2[2 * c + 1] + h1 * W2[2 * c + 3];
        }
        p0 += __shfl_down(p0, 2, 4); p0 += __shfl_down(p0, 1, 4);
        p1 += __shfl_down(p1, 2, 4); p1 += __shfl_down(p1, 1, 4);
        if (q == 0) m2q[r] = make_float2(di * p0, di * p1);
    }
}

// one block per bucket, 512 threads.  Edge-parallel fixed-point LDS atomics;
// m2q is 0.8 MB -> L2-resident gather.
__global__ void __launch_bounds__(512, 8)
agg2_kernel(const int* __restrict__ gbase, const int* __restrict__ gcnt,
            const unsigned int* __restrict__ binned,
            const float2* __restrict__ m2q,
            const float* __restrict__ dinv, const float* __restrict__ b2,
            float* __restrict__ out, int n) {
    __shared__ int a0s[NPB], a1s[NPB];
    const int t = threadIdx.x;
    const int b = blockIdx.x;
    const int beg = gbase[b];
    const int cntb = gcnt[b];
    const int r0 = b << NPB_SHIFT;

    if (t < NPB) { a0s[t] = 0; a1s[t] = 0; }
    __syncthreads();

    const unsigned int* __restrict__ bp = binned + beg;
    int i = t;
    for (; i + 1536 < cntb; i += 2048) {
        unsigned int e0 = __builtin_nontemporal_load(&bp[i]);
        unsigned int e1 = __builtin_nontemporal_load(&bp[i + 512]);
        unsigned int e2 = __builtin_nontemporal_load(&bp[i + 1024]);
        unsigned int e3 = __builtin_nontemporal_load(&bp[i + 1536]);
        float2 v0 = m2q[e0 & 0x1FFFFu];
        float2 v1 = m2q[e1 & 0x1FFFFu];
        float2 v2 = m2q[e2 & 0x1FFFFu];
        float2 v3 = m2q[e3 & 0x1FFFFu];
        atomicAdd(&a0s[e0 >> 17], __float2int_rn(v0.x * FXS2));
        atomicAdd(&a1s[e0 >> 17], __float2int_rn(v0.y * FXS2));
        atomicAdd(&a0s[e1 >> 17], __float2int_rn(v1.x * FXS2));
        atomicAdd(&a1s[e1 >> 17], __float2int_rn(v1.y * FXS2));
        atomicAdd(&a0s[e2 >> 17], __float2int_rn(v2.x * FXS2));
        atomicAdd(&a1s[e2 >> 17], __float2int_rn(v2.y * FXS2));
        atomicAdd(&a0s[e3 >> 17], __float2int_rn(v3.x * FXS2));
        atomicAdd(&a1s[e3 >> 17], __float2int_rn(v3.y * FXS2));
    }
    for (; i < cntb; i += 512) {
        unsigned int e0 = __builtin_nontemporal_load(&bp[i]);
        float2 v0 = m2q[e0 & 0x1FFFFu];
        atomicAdd(&a0s[e0 >> 17], __float2int_rn(v0.x * FXS2));
        atomicAdd(&a1s[e0 >> 17], __float2int_rn(v0.y * FXS2));
    }
    __syncthreads();

    if (t < NPB) {
        int r = r0 + t;
        if (r < n) {
            float di = dinv[r];
            float2 self = m2q[r];
            out[(size_t)r * DOUT + 0] = di * ((float)a0s[t] * FXI2 + self.x) + b2[0];
            out[(size_t)r * DOUT + 1] = di * ((float)a1s[t] * FXI2 + self.y) + b2[1];
        }
    }
}

extern "C" void kernel_launch(void* const* d_in, const int* in_sizes, int n_in,
                              void* d_out, int out_size, void* d_ws, size_t ws_size,
                              hipStream_t stream) {
    const float* x  = (const float*)d_in[0];
    const int*   ei = (const int*)d_in[1];
    const float* W1 = (const float*)d_in[2];
    const float* b1 = (const float*)d_in[3];
    const float* W2 = (const float*)d_in[4];
    const float* b2 = (const float*)d_in[5];
    float* out = (float*)d_out;

    const int n = in_sizes[0] / DIN;
    const int e = in_sizes[1] / 2;
    const int* src = ei;
    const int* dst = ei + e;
    const int nbuk = (n + NPB - 1) >> NPB_SHIFT;   // 782 for n=100000

    char* ws = (char*)d_ws;
    float* dinv   = (float*)ws;          ws += (size_t)n * 4;
    int* gcnt     = (int*)ws;            ws += NBUK_MAX * 4;
    int* degarr   = (int*)ws;            ws += (size_t)n * 4;   // contiguous w/ gcnt
    int* gbase    = (int*)ws;            ws += NBUK_MAX * 4;
    int* gcur     = (int*)ws;            ws += NBUK_MAX * 4;
    unsigned int* binned = (unsigned int*)ws;   ws += (size_t)e * 4;
    unsigned short* mqc  = (unsigned short*)ws; ws += ((size_t)n + 1) * DH * 2;
    float2* m2q   = (float2*)ws;

    const int B = 256;
    const int fill_blocks = (e + FILL_EDGES - 1) / FILL_EDGES;   // 1563

    hipMemsetAsync(gcnt, 0, (size_t)(NBUK_MAX + n) * 4, stream);  // gcnt + degarr
    bukhist_kernel<<<fill_blocks, B, 0, stream>>>(dst, gcnt, degarr, e, nbuk);
    scan_kernel<<<1, B, 0, stream>>>(gcnt, gbase, gcur, nbuk, mqc, n);
    binfill_kernel<<<fill_blocks, B, 0, stream>>>(src, dst, gcur, binned, e, nbuk);
    gemm1_kernel<<<(n + 31) / 32, B, 0, stream>>>(x, W1, degarr, dinv, mqc, n);
    agg1_kernel<<<nbuk, 512, 0, stream>>>(gbase, gcnt, binned, mqc, dinv, b1, W2, m2q, n);
    agg2_kernel<<<nbuk, 512, 0, stream>>>(gbase, gcnt, binned, m2q, dinv, b2, out, n);
}

// Round 4
// 242.658 us; speedup vs baseline: 4.6070x; 4.6070x over previous
//
#include <hip/hip_runtime.h>
#include <hip/hip_bf16.h>

#define DIN 128
#define DH 32
#define DOUT 2
#define NPB 128            // nodes per bucket
#define NPB_SHIFT 7
#define NBUK_MAX 1024      // supports n <= 131072 (17-bit src packing)
#define FILL_EDGES 8192    // edges per binning block
#define ECHUNK 2048        // agg1 staged edge chunk

// fixed-point scales for LDS integer accumulation (atomicAdd(int*) -> ds_add_u32;
// float atomicAdd on LDS is a CAS loop = round-1's 12x regression)
#define FXS1 262144.0f            // 2^18
#define FXI1 (1.0f / 262144.0f)
#define FXS2 131072.0f            // 2^17
#define FXI2 (1.0f / 131072.0f)

// ---------------------------------------------------------------------------
// workspace (~20.5 MB, budget ~26.8 MB)  — round-2 layout, unchanged:
//   dinv float[n]; gcnt/gbase/gcur int[NBUK_MAX]
//   binned uint[E]: (dst&127)<<17 | src grouped by bucket (never rewritten)
//   mqc bf16[(n+1)*32]: dinv-scaled layer-1 messages + ZERO sentinel row n
//   m2q float2[n]
// ---------------------------------------------------------------------------

__device__ inline unsigned short f2bf(float f) {
    unsigned int u = __float_as_uint(f);
    u = (u + 0x7FFFu + ((u >> 16) & 1u)) >> 16;
    return (unsigned short)u;
}
__device__ inline float bfLO(unsigned int w) { return __uint_as_float(w << 16); }
__device__ inline float bfHI(unsigned int w) { return __uint_as_float(w & 0xFFFF0000u); }

__global__ void zero_gcnt_kernel(int* __restrict__ gcnt, int nbuk) {
    int i = blockIdx.x * blockDim.x + threadIdx.x;
    if (i < nbuk) gcnt[i] = 0;
}

// bucket-level histogram, LDS-staged
__global__ void bukhist_kernel(const int* __restrict__ dst, int* __restrict__ gcnt,
                               int e, int nbuk) {
    __shared__ int lcnt[NBUK_MAX];
    int t = threadIdx.x;
    for (int i = t; i < nbuk; i += 256) lcnt[i] = 0;
    __syncthreads();
    int e0 = blockIdx.x * FILL_EDGES;
    int m = min(FILL_EDGES, e - e0);
    for (int i = t; i < m; i += 256) atomicAdd(&lcnt[dst[e0 + i] >> NPB_SHIFT], 1);
    __syncthreads();
    for (int i = t; i < nbuk; i += 256)
        if (lcnt[i]) atomicAdd(&gcnt[i], lcnt[i]);
}

// single-block exclusive scan of gcnt[nbuk] -> gbase, gcur; also zeroes the
// mqc sentinel row n (agg1's padded slots gather it -> adds exact 0)
__global__ void scan_kernel(const int* __restrict__ gcnt, int* __restrict__ gbase,
                            int* __restrict__ gcur, int nbuk,
                            unsigned short* __restrict__ mqc, int n) {
    __shared__ int sd[256];
    int t = threadIdx.x;
    if (t < 16) ((unsigned int*)(mqc + (size_t)n * DH))[t] = 0u;
    int v[4], s = 0;
#pragma unroll
    for (int k = 0; k < 4; ++k) {
        int i = 4 * t + k;
        v[k] = (i < nbuk) ? gcnt[i] : 0;
        s += v[k];
    }
    sd[t] = s;
    __syncthreads();
    for (int off = 1; off < 256; off <<= 1) {
        int x = (t >= off) ? sd[t - off] : 0;
        __syncthreads();
        sd[t] += x;
        __syncthreads();
    }
    int run = sd[t] - s;
#pragma unroll
    for (int k = 0; k < 4; ++k) {
        int i = 4 * t + k;
        if (i < nbuk) { gbase[i] = run; gcur[i] = run; }
        run += v[k];
    }
}

// LDS counting-sort of 8192 edges by bucket, bulk-append to global regions
__global__ void binfill_kernel(const int* __restrict__ src, const int* __restrict__ dst,
                               int* __restrict__ gcur, unsigned int* __restrict__ binned,
                               int e, int nbuk) {
    __shared__ int cnt[NBUK_MAX];
    __shared__ int pos[NBUK_MAX];
    __shared__ int gb[NBUK_MAX];
    __shared__ unsigned int sorted[FILL_EDGES];
    __shared__ unsigned short aux[FILL_EDGES];
    __shared__ int stmp[256];

    int t = threadIdx.x;
    int e0 = blockIdx.x * FILL_EDGES;
    int m = min(FILL_EDGES, e - e0);

    for (int i = t; i < nbuk; i += 256) cnt[i] = 0;
    __syncthreads();
    for (int i = t; i < m; i += 256) atomicAdd(&cnt[dst[e0 + i] >> NPB_SHIFT], 1);
    __syncthreads();

    int v[4], s = 0;
#pragma unroll
    for (int k = 0; k < 4; ++k) {
        int i = 4 * t + k;
        v[k] = (i < nbuk) ? cnt[i] : 0;
        s += v[k];
    }
    stmp[t] = s;
    __syncthreads();
    for (int off = 1; off < 256; off <<= 1) {
        int x = (t >= off) ? stmp[t - off] : 0;
        __syncthreads();
        stmp[t] += x;
        __syncthreads();
    }
    int run = stmp[t] - s;
#pragma unroll
    for (int k = 0; k < 4; ++k) {
        int i = 4 * t + k;
        if (i < nbuk) pos[i] = run;
        run += v[k];
    }
    __syncthreads();

    for (int i = t; i < m; i += 256) {
        int d = dst[e0 + i];
        int sv = src[e0 + i];
        int b = d >> NPB_SHIFT;
        int r = atomicAdd(&pos[b], 1);
        sorted[r] = ((unsigned int)(d & (NPB - 1)) << 17) | (unsigned int)sv;
        aux[r] = (unsigned short)b;
    }
    __syncthreads();

    for (int b = t; b < nbuk; b += 256) {
        int c = cnt[b];
        gb[b] = c ? atomicAdd(&gcur[b], c) : 0;
    }
    __syncthreads();

    for (int i = t; i < m; i += 256) {
        int b = aux[i];
        int start = pos[b] - cnt[b];
        binned[gb[b] + (i - start)] = sorted[i];
    }
}

// per-bucket node degree from binned -> dinv = rsqrt(deg+1)
__global__ void bdinv_kernel(const int* __restrict__ gbase, const int* __restrict__ gcnt,
                             const unsigned int* __restrict__ binned,
                             float* __restrict__ dinv, int n) {
    __shared__ int cnt[NPB];
    int t = threadIdx.x;
    int b = blockIdx.x;
    if (t < NPB) cnt[t] = 0;
    __syncthreads();
    const int beg = gbase[b];
    const int cntb = gcnt[b];
    for (int i = t; i < cntb; i += 256) atomicAdd(&cnt[binned[beg + i] >> 17], 1);
    __syncthreads();
    if (t < NPB) {
        int r = (b << NPB_SHIFT) + t;
        if (r < n) dinv[r] = rsqrtf((float)(cnt[t] + 1));
    }
}

// mqc[r][c] = (x[r]·W1[:,c]) * dinv[r], bf16.  32 rows/block staged in
// padded LDS; thread = (row, 4 cols); register-lean, no spills.
#define XLD 132
__global__ void gemm1_kernel(const float* __restrict__ x, const float* __restrict__ W1,
                             const float* __restrict__ dinv,
                             unsigned short* __restrict__ mqc, int n) {
    __shared__ float  Xl[32 * XLD];
    __shared__ float4 Wl4[DIN * 8];

    int t = threadIdx.x;
    for (int i = t; i < DIN * 8; i += 256) Wl4[i] = ((const float4*)W1)[i];

    int rb = blockIdx.x * 32;
    for (int i = t; i < 32 * 32; i += 256) {
        int rr = i >> 5, c4 = i & 31;
        int gr = rb + rr;
        float4 v = make_float4(0.f, 0.f, 0.f, 0.f);
        if (gr < n) v = ((const float4*)x)[(size_t)gr * 32 + c4];
        ((float4*)Xl)[rr * 33 + c4] = v;
    }
    __syncthreads();

    const int lane = t & 7;
    const int row  = t >> 3;
    const float* xrow = &Xl[row * XLD];
    float4 acc = make_float4(0.f, 0.f, 0.f, 0.f);
#pragma unroll
    for (int k = 0; k < DIN; ++k) {
        float xv = xrow[k];
        float4 w = Wl4[k * 8 + lane];
        acc.x += xv * w.x; acc.y += xv * w.y;
        acc.z += xv * w.z; acc.w += xv * w.w;
    }
    int r = rb + row;
    if (r < n) {
        float di = dinv[r];
        ushort4 sv;
        sv.x = f2bf(acc.x * di); sv.y = f2bf(acc.y * di);
        sv.z = f2bf(acc.z * di); sv.w = f2bf(acc.w * di);
        *(ushort4*)&mqc[(size_t)r * DH + 4 * lane] = sv;
    }
}

// one block per bucket, 512 threads.  Edges staged into LDS in double-buffered
// 2048-edge chunks (hot loop reads edge words via LDS broadcast; NT prefetch
// of chunk c+1 overlaps chunk c's gathers); 32 gather-groups of 16 lanes;
// x8 unroll = 8 mqc gathers in flight/group; fixed-point ds_add accumulation;
// sentinel edge word = n (mqc row n zeroed) -> zero predication in hot loop.
// LDS 33 KB -> 4 blocks/CU; 782 blocks all co-resident.
__global__ void __launch_bounds__(512, 8)
agg1_kernel(const int* __restrict__ gbase, const int* __restrict__ gcnt,
            const unsigned int* __restrict__ binned,
            const unsigned short* __restrict__ mqc,
            const float* __restrict__ dinv,
            const float* __restrict__ b1, const float* __restrict__ W2,
            float2* __restrict__ m2q, int n) {
    __shared__ int acc[NPB * 33];                 // 16.9 KB
    __shared__ unsigned int ebuf[2][ECHUNK];      // 16 KB

    const int t = threadIdx.x;
    const int b = blockIdx.x;
    const int beg = gbase[b];
    const int cntb = gcnt[b];
    const int r0 = b << NPB_SHIFT;

    for (int i = t; i < NPB * 33; i += 512) acc[i] = 0;

    const unsigned int* __restrict__ bp = binned + beg;
    const unsigned int* __restrict__ mq32 = (const unsigned int*)mqc;
    const unsigned int sent = (unsigned int)n;    // n < 2^17 -> dst-local 0, zero row
    const int nchunks = (cntb + ECHUNK - 1) / ECHUNK;

    unsigned int st[4];
    if (nchunks > 0) {
#pragma unroll
        for (int k = 0; k < 4; ++k) {
            int idx = t + k * 512;
            st[k] = (idx < cntb) ? __builtin_nontemporal_load(&bp[idx]) : sent;
        }
#pragma unroll
        for (int k = 0; k < 4; ++k) ebuf[0][t + k * 512] = st[k];
    }
    __syncthreads();

    const int g = t >> 4, l = t & 15;

    for (int c = 0; c < nchunks; ++c) {
        if (c + 1 < nchunks) {
            const int base = (c + 1) * ECHUNK;
#pragma unroll
            for (int k = 0; k < 4; ++k) {
                int idx = base + t + k * 512;
                st[k] = (idx < cntb) ? __builtin_nontemporal_load(&bp[idx]) : sent;
            }
        }
        const unsigned int* eb = ebuf[c & 1];
        for (int j = 0; j < 64; j += 8) {
            const unsigned int* ej = &eb[g + 32 * j];
            unsigned int e0 = ej[0],   e1 = ej[32],  e2 = ej[64],  e3 = ej[96];
            unsigned int e4 = ej[128], e5 = ej[160], e6 = ej[192], e7 = ej[224];
            unsigned int w0 = mq32[(e0 & 0x1FFFFu) * 16u + l];
            unsigned int w1 = mq32[(e1 & 0x1FFFFu) * 16u + l];
            unsigned int w2 = mq32[(e2 & 0x1FFFFu) * 16u + l];
            unsigned int w3 = mq32[(e3 & 0x1FFFFu) * 16u + l];
            unsigned int w4 = mq32[(e4 & 0x1FFFFu) * 16u + l];
            unsigned int w5 = mq32[(e5 & 0x1FFFFu) * 16u + l];
            unsigned int w6 = mq32[(e6 & 0x1FFFFu) * 16u + l];
            unsigned int w7 = mq32[(e7 & 0x1FFFFu) * 16u + l];
            int d0 = (int)(e0 >> 17) * 33 + 2 * l;
            int d1 = (int)(e1 >> 17) * 33 + 2 * l;
            int d2 = (int)(e2 >> 17) * 33 + 2 * l;
            int d3 = (int)(e3 >> 17) * 33 + 2 * l;
            int d4 = (int)(e4 >> 17) * 33 + 2 * l;
            int d5 = (int)(e5 >> 17) * 33 + 2 * l;
            int d6 = (int)(e6 >> 17) * 33 + 2 * l;
            int d7 = (int)(e7 >> 17) * 33 + 2 * l;
            atomicAdd(&acc[d0], __float2int_rn(bfLO(w0) * FXS1));
            atomicAdd(&acc[d0 + 1], __float2int_rn(bfHI(w0) * FXS1));
            atomicAdd(&acc[d1], __float2int_rn(bfLO(w1) * FXS1));
            atomicAdd(&acc[d1 + 1], __float2int_rn(bfHI(w1) * FXS1));
            atomicAdd(&acc[d2], __float2int_rn(bfLO(w2) * FXS1));
            atomicAdd(&acc[d2 + 1], __float2int_rn(bfHI(w2) * FXS1));
            atomicAdd(&acc[d3], __float2int_rn(bfLO(w3) * FXS1));
            atomicAdd(&acc[d3 + 1], __float2int_rn(bfHI(w3) * FXS1));
            atomicAdd(&acc[d4], __float2int_rn(bfLO(w4) * FXS1));
            atomicAdd(&acc[d4 + 1], __float2int_rn(bfHI(w4) * FXS1));
            atomicAdd(&acc[d5], __float2int_rn(bfLO(w5) * FXS1));
            atomicAdd(&acc[d5 + 1], __float2int_rn(bfHI(w5) * FXS1));
            atomicAdd(&acc[d6], __float2int_rn(bfLO(w6) * FXS1));
            atomicAdd(&acc[d6 + 1], __float2int_rn(bfHI(w6) * FXS1));
            atomicAdd(&acc[d7], __float2int_rn(bfLO(w7) * FXS1));
            atomicAdd(&acc[d7 + 1], __float2int_rn(bfHI(w7) * FXS1));
        }
        __syncthreads();
        if (c + 1 < nchunks) {
#pragma unroll
            for (int k = 0; k < 4; ++k) ebuf[(c + 1) & 1][t + k * 512] = st[k];
        }
        __syncthreads();
    }

    // epilogue: 4 threads per node (8 dims each): self + ReLU + W2
    const int j = t >> 2, q = t & 3;
    const int r = r0 + j;
    if (r < n) {
        const float di = dinv[r];
        const unsigned int* srow = mq32 + (size_t)r * 16 + q * 4;
        const int* ar = &acc[j * 33 + q * 8];
        float p0 = 0.f, p1 = 0.f;
#pragma unroll
        for (int k = 0; k < 4; ++k) {
            unsigned int sw = srow[k];
            int c = q * 8 + 2 * k;
            float a0 = (float)ar[2 * k]     * FXI1;
            float a1 = (float)ar[2 * k + 1] * FXI1;
            float h0 = fmaxf(di * (a0 + bfLO(sw)) + b1[c],     0.0f);
            float h1 = fmaxf(di * (a1 + bfHI(sw)) + b1[c + 1], 0.0f);
            p0 += h0 * W2[2 * c]     + h1 * W2[2 * c + 2];
            p1 += h0 * W2[2 * c + 1] + h1 * W2[2 * c + 3];
        }
        p0 += __shfl_down(p0, 2, 4); p0 += __shfl_down(p0, 1, 4);
        p1 += __shfl_down(p1, 2, 4); p1 += __shfl_down(p1, 1, 4);
        if (q == 0) m2q[r] = make_float2(di * p0, di * p1);
    }
}

// one block per bucket.  Edge-parallel, fixed-point int LDS atomics
// (ds_add_u32); m2q is 0.8 MB -> L2-resident gather.  (round-2 version)
__global__ void __launch_bounds__(256, 4)
agg2_kernel(const int* __restrict__ gbase, const int* __restrict__ gcnt,
            const unsigned int* __restrict__ binned,
            const float2* __restrict__ m2q,
            const float* __restrict__ dinv, const float* __restrict__ b2,
            float* __restrict__ out, int n) {
    __shared__ int a0s[NPB], a1s[NPB];
    const int t = threadIdx.x;
    const int b = blockIdx.x;
    const int beg = gbase[b];
    const int cntb = gcnt[b];
    const int r0 = b << NPB_SHIFT;

    if (t < NPB) { a0s[t] = 0; a1s[t] = 0; }
    __syncthreads();

    const unsigned int* __restrict__ bp = binned + beg;
    int i = t;
    for (; i + 768 < cntb; i += 1024) {
        unsigned int e0 = __builtin_nontemporal_load(&bp[i]);
        unsigned int e1 = __builtin_nontemporal_load(&bp[i + 256]);
        unsigned int e2 = __builtin_nontemporal_load(&bp[i + 512]);
        unsigned int e3 = __builtin_nontemporal_load(&bp[i + 768]);
        float2 v0 = m2q[e0 & 0x1FFFFu];
        float2 v1 = m2q[e1 & 0x1FFFFu];
        float2 v2 = m2q[e2 & 0x1FFFFu];
        float2 v3 = m2q[e3 & 0x1FFFFu];
        atomicAdd(&a0s[e0 >> 17], __float2int_rn(v0.x * FXS2));
        atomicAdd(&a1s[e0 >> 17], __float2int_rn(v0.y * FXS2));
        atomicAdd(&a0s[e1 >> 17], __float2int_rn(v1.x * FXS2));
        atomicAdd(&a1s[e1 >> 17], __float2int_rn(v1.y * FXS2));
        atomicAdd(&a0s[e2 >> 17], __float2int_rn(v2.x * FXS2));
        atomicAdd(&a1s[e2 >> 17], __float2int_rn(v2.y * FXS2));
        atomicAdd(&a0s[e3 >> 17], __float2int_rn(v3.x * FXS2));
        atomicAdd(&a1s[e3 >> 17], __float2int_rn(v3.y * FXS2));
    }
    for (; i < cntb; i += 256) {
        unsigned int e0 = __builtin_nontemporal_load(&bp[i]);
        float2 v0 = m2q[e0 & 0x1FFFFu];
        atomicAdd(&a0s[e0 >> 17], __float2int_rn(v0.x * FXS2));
        atomicAdd(&a1s[e0 >> 17], __float2int_rn(v0.y * FXS2));
    }
    __syncthreads();

    if (t < NPB) {
        int r = r0 + t;
        if (r < n) {
            float di = dinv[r];
            float2 self = m2q[r];
            out[(size_t)r * DOUT + 0] = di * ((float)a0s[t] * FXI2 + self.x) + b2[0];
            out[(size_t)r * DOUT + 1] = di * ((float)a1s[t] * FXI2 + self.y) + b2[1];
        }
    }
}

extern "C" void kernel_launch(void* const* d_in, const int* in_sizes, int n_in,
                              void* d_out, int out_size, void* d_ws, size_t ws_size,
                              hipStream_t stream) {
    const float* x  = (const float*)d_in[0];
    const int*   ei = (const int*)d_in[1];
    const float* W1 = (const float*)d_in[2];
    const float* b1 = (const float*)d_in[3];
    const float* W2 = (const float*)d_in[4];
    const float* b2 = (const float*)d_in[5];
    float* out = (float*)d_out;

    const int n = in_sizes[0] / DIN;
    const int e = in_sizes[1] / 2;
    const int* src = ei;
    const int* dst = ei + e;
    const int nbuk = (n + NPB - 1) >> NPB_SHIFT;   // 782 for n=100000

    char* ws = (char*)d_ws;
    float* dinv   = (float*)ws;          ws += (size_t)n * 4;
    int* gcnt     = (int*)ws;            ws += NBUK_MAX * 4;
    int* gbase    = (int*)ws;            ws += NBUK_MAX * 4;
    int* gcur     = (int*)ws;            ws += NBUK_MAX * 4;
    unsigned int* binned = (unsigned int*)ws;   ws += (size_t)e * 4;
    unsigned short* mqc  = (unsigned short*)ws; ws += ((size_t)n + 1) * DH * 2;
    float2* m2q   = (float2*)ws;

    const int B = 256;
    const int fill_blocks = (e + FILL_EDGES - 1) / FILL_EDGES;   // 391

    zero_gcnt_kernel<<<(nbuk + B - 1) / B, B, 0, stream>>>(gcnt, nbuk);
    bukhist_kernel<<<fill_blocks, B, 0, stream>>>(dst, gcnt, e, nbuk);
    scan_kernel<<<1, B, 0, stream>>>(gcnt, gbase, gcur, nbuk, mqc, n);
    binfill_kernel<<<fill_blocks, B, 0, stream>>>(src, dst, gcur, binned, e, nbuk);
    bdinv_kernel<<<nbuk, B, 0, stream>>>(gbase, gcnt, binned, dinv, n);
    gemm1_kernel<<<(n + 31) / 32, B, 0, stream>>>(x, W1, dinv, mqc, n);
    agg1_kernel<<<nbuk, 512, 0, stream>>>(gbase, gcnt, binned, mqc, dinv, b1, W2, m2q, n);
    agg2_kernel<<<nbuk, B, 0, stream>>>(gbase, gcnt, binned, m2q, dinv, b2, out, n);
}